// Round 6
// baseline (322.526 us; speedup 1.0000x reference)
//
#include <hip/hip_runtime.h>

// GHM loss: focal (ch 0) + GHMR (ch 1..7), 3 scalar outputs.
//
// Pass 1: ONE-SHOT grid (no grid-stride convoy; round-4 result: 112->70us):
//   thread g handles pixels 2g, 2g+1 via 8 independent nontemporal dwordx4
//   loads issued at wave start. Bin test algebraic:
//     g*10 >= b  <=>  d^2 >= C_b = b^2*mu^2/(100-b^2).
//   Bin 0's predicate is exactly `valid` -> no compare/ballot; its count
//   c_0 = 7 * (valid pixel count), derived in the finalizer.
//   Counts b=1..9: ballot -> popcll (wave-uniform, scalar pipe).
//   Loss sums: cndmask+add reusing the bin compare.
// Pass 2 (fused final): 1 block; 4 waves cycle over the 22 quantities,
//   lane-strided over blocks; then lane 0 computes the 3 outputs.
//
// Partials layout [quantity][block], NQ = 22:
//   q 0..9  : cumulative loss sums  l_b  (loss where g*10 >= b, valid)
//   q 10    : focal sum
//   q 11    : valid pixel count
//   q 12    : unused (written 0; c_0 derived as 7*q11)
//   q 13..21: cumulative counts     c_b, b=1..9

#define NQ 22

// native vector type: __builtin_nontemporal_load rejects HIP_vector_type
typedef float vf4 __attribute__((ext_vector_type(4)));

__device__ __forceinline__ float wave_sum(float v) {
    v += __shfl_down(v, 32);
    v += __shfl_down(v, 16);
    v += __shfl_down(v, 8);
    v += __shfl_down(v, 4);
    v += __shfl_down(v, 2);
    v += __shfl_down(v, 1);
    return v;
}

__global__ __launch_bounds__(256)
void ghm_pass1(const vf4* __restrict__ preds, const vf4* __restrict__ tgts,
               int n_pix, float* __restrict__ part, int nb) {
    constexpr float MU2 = 4.0e-4f;
    const float C[10] = { -0.5f,
                          4.0404041e-6f, 1.6666667e-5f, 3.9560441e-5f,
                          7.6190476e-5f, 1.3333333e-4f, 2.2500000e-4f,
                          3.8431373e-4f, 7.1111111e-4f, 1.7052632e-3f };

    float lac[10];
#pragma unroll
    for (int b = 0; b < 10; ++b) lac[b] = 0.f;
    float facc = 0.f;
    unsigned int cnt[10] = {0,0,0,0,0,0,0,0,0,0};
    unsigned int vcnt = 0;

    const int tid = threadIdx.x;
    const long total4 = 2L * (long)n_pix;   // float4 count per array

    for (long g = (long)blockIdx.x * 256 + tid; 2 * g < (long)n_pix;
         g += (long)gridDim.x * 256) {
        const long b4 = 4 * g;
        const bool in1 = (2 * g + 1) < (long)n_pix;
        const long i1 = (b4 + 1 < total4) ? b4 + 1 : total4 - 1;
        const long i2 = (b4 + 2 < total4) ? b4 + 2 : total4 - 1;
        const long i3 = (b4 + 3 < total4) ? b4 + 3 : total4 - 1;

        vf4 pA = __builtin_nontemporal_load(&preds[b4]);
        vf4 pB = __builtin_nontemporal_load(&preds[i1]);
        vf4 pC = __builtin_nontemporal_load(&preds[i2]);
        vf4 pD = __builtin_nontemporal_load(&preds[i3]);
        vf4 tA = __builtin_nontemporal_load(&tgts[b4]);
        vf4 tB = __builtin_nontemporal_load(&tgts[i1]);
        vf4 tC = __builtin_nontemporal_load(&tgts[i2]);
        vf4 tD = __builtin_nontemporal_load(&tgts[i3]);

        bool v1 = tA.x > 0.1f;            // pixel 2g
        bool v2 = in1 && (tC.x > 0.1f);   // pixel 2g+1

        // focal, pixel 2g
        {
            float x  = pA.x;
            float xt = v1 ? x : 1.f - x;
            float at = v1 ? 0.25f : 0.75f;
            float om = 1.f - xt;
            facc += -at * om * om * __logf(xt + 1e-5f);
        }
        // focal, pixel 2g+1 (masked if out of bounds)
        {
            bool vv  = tC.x > 0.1f;
            float x  = pC.x;
            float xt = vv ? x : 1.f - x;
            float at = vv ? 0.25f : 0.75f;
            float om = 1.f - xt;
            float f  = -at * om * om * __logf(xt + 1e-5f);
            facc += in1 ? f : 0.f;
        }
        vcnt += (unsigned)__builtin_popcountll(__ballot(v1));
        vcnt += (unsigned)__builtin_popcountll(__ballot(v2));

        float pd[14] = {pA.y,pA.z,pA.w, pB.x,pB.y,pB.z,pB.w,
                        pC.y,pC.z,pC.w, pD.x,pD.y,pD.z,pD.w};
        float td[14] = {tA.y,tA.z,tA.w, tB.x,tB.y,tB.z,tB.w,
                        tC.y,tC.z,tC.w, tD.x,tD.y,tD.z,tD.w};
#pragma unroll
        for (int e = 0; e < 14; ++e) {
            bool m   = (e < 7) ? v1 : v2;
            float d  = pd[e] - td[e];
            float d2 = d * d;
            float s  = __builtin_amdgcn_sqrtf(__builtin_fmaf(d, d, MU2));
            float loss = s - 0.02f;
            // bin 0: predicate is exactly m — no compare/ballot needed
            lac[0] += m ? loss : 0.f;
            float d2m = m ? d2 : -1.f;
#pragma unroll
            for (int b = 1; b < 10; ++b) {
                bool pb = d2m >= C[b];
                lac[b] += pb ? loss : 0.f;
                cnt[b] += (unsigned)__builtin_popcountll(__ballot(pb));
            }
        }
    }

    float vq[11] = { lac[0], lac[1], lac[2], lac[3], lac[4],
                     lac[5], lac[6], lac[7], lac[8], lac[9], facc };
#pragma unroll
    for (int q = 0; q < 11; ++q) vq[q] = wave_sum(vq[q]);

    __shared__ float sm[4][NQ];
    const int wave = tid >> 6, lane = tid & 63;
    if (lane == 0) {
#pragma unroll
        for (int q = 0; q < 11; ++q) sm[wave][q] = vq[q];
        sm[wave][11] = (float)vcnt;
        sm[wave][12] = 0.f;
#pragma unroll
        for (int b = 1; b < 10; ++b) sm[wave][12 + b] = (float)cnt[b];
    }
    __syncthreads();
    if (tid < NQ) {
        float v = sm[0][tid] + sm[1][tid] + sm[2][tid] + sm[3][tid];
        part[(size_t)tid * nb + blockIdx.x] = v;
    }
}

// Fused reduction + finalize: one block, 4 waves cycle over quantities.
__global__ __launch_bounds__(256)
void ghm_final(const float* __restrict__ part, int nb,
               float* __restrict__ out, float inv_npix) {
    __shared__ float red[NQ];
    const int tid = threadIdx.x;
    const int wave = tid >> 6, lane = tid & 63;

    for (int q = wave; q < NQ; q += 4) {
        float v = 0.f;
        for (int i = lane; i < nb; i += 64) v += part[(size_t)q * nb + i];
        v = wave_sum(v);
        if (lane == 0) red[q] = v;
    }
    __syncthreads();

    if (tid == 0) {
        float tot = fmaxf(red[11], 1.f);
        float c0  = 7.f * red[11];           // bin-0 cumulative count
        float n = 0.f, sum = 0.f;
#pragma unroll
        for (int b = 0; b < 10; ++b) {
            float ccb = (b == 0) ? c0 : red[12 + b];
            float cb  = ccb        - (b < 9 ? red[12 + b + 1] : 0.f);
            float lb  = red[b]     - (b < 9 ? red[b + 1]      : 0.f);
            if (cb > 0.f) {
                n += 1.f;
                sum += tot / fmaxf(0.3f * cb, 1e-30f) * lb;
            }
        }
        float reg = sum / fmaxf(n, 1.f) / tot;
        float cls = red[10] * inv_npix;
        out[0] = cls + reg;
        out[1] = reg;
        out[2] = cls;
    }
}

extern "C" void kernel_launch(void* const* d_in, const int* in_sizes, int n_in,
                              void* d_out, int out_size, void* d_ws, size_t ws_size,
                              hipStream_t stream) {
    const float* preds = (const float*)d_in[0];
    const float* tgts  = (const float*)d_in[1];
    const int n_pix = in_sizes[0] / 8;

    long want_nb = ((long)n_pix + 511) / 512;          // one-shot: 2 px/thread
    long cap = (long)(ws_size / sizeof(float)) / NQ;
    long nb_l = want_nb < cap ? want_nb : cap;
    if (nb_l < 1) nb_l = 1;
    int nb = (int)nb_l;

    float* part = (float*)d_ws;
    ghm_pass1<<<nb, 256, 0, stream>>>((const vf4*)preds, (const vf4*)tgts,
                                      n_pix, part, nb);
    ghm_final<<<1, 256, 0, stream>>>(part, nb, (float*)d_out,
                                     1.f / (float)n_pix);
}

// Round 7
// 106.922 us; speedup vs baseline: 3.0165x; 3.0165x over previous
//
#include <hip/hip_runtime.h>

// GHM loss: focal (ch 0) + GHMR (ch 1..7), 3 scalar outputs.
//
// Pass 1: ONE-SHOT grid (no grid-stride convoy; round-4: 112->70us):
//   thread g handles pixels 2g, 2g+1 via 8 independent nontemporal dwordx4
//   loads issued at wave start. Bin test algebraic:
//     g*10 >= b  <=>  d^2 >= C_b = b^2*mu^2/(100-b^2).
//   Bin 0's predicate is exactly `valid` -> no compare/ballot; its count
//   c_0 = 7 * (valid pixel count), derived in the finalizer.
//   Counts b=1..9: ballot -> popcll (wave-uniform, scalar pipe).
// Pass 2: 22 blocks IN PARALLEL, block q reduces part[q][*] -> red[q].
//   (Round-6 lesson: fusing this into pass3's single block made one CU
//    read 774 KB latency-bound = 232 us. Keep the parallel stage.)
// Pass 3: 1 tiny block computes the 3 outputs from red[22].
//
// Partials layout [quantity][block], NQ = 22:
//   q 0..9  : cumulative loss sums  l_b  (loss where g*10 >= b, valid)
//   q 10    : focal sum
//   q 11    : valid pixel count
//   q 12    : unused (written 0; c_0 derived as 7*q11)
//   q 13..21: cumulative counts     c_b, b=1..9

#define NQ 22

// native vector type: __builtin_nontemporal_load rejects HIP_vector_type
typedef float vf4 __attribute__((ext_vector_type(4)));

__device__ __forceinline__ float wave_sum(float v) {
    v += __shfl_down(v, 32);
    v += __shfl_down(v, 16);
    v += __shfl_down(v, 8);
    v += __shfl_down(v, 4);
    v += __shfl_down(v, 2);
    v += __shfl_down(v, 1);
    return v;
}

__global__ __launch_bounds__(256)
void ghm_pass1(const vf4* __restrict__ preds, const vf4* __restrict__ tgts,
               int n_pix, float* __restrict__ part, int nb) {
    constexpr float MU2 = 4.0e-4f;
    const float C[10] = { -0.5f,
                          4.0404041e-6f, 1.6666667e-5f, 3.9560441e-5f,
                          7.6190476e-5f, 1.3333333e-4f, 2.2500000e-4f,
                          3.8431373e-4f, 7.1111111e-4f, 1.7052632e-3f };

    float lac[10];
#pragma unroll
    for (int b = 0; b < 10; ++b) lac[b] = 0.f;
    float facc = 0.f;
    unsigned int cnt[10] = {0,0,0,0,0,0,0,0,0,0};
    unsigned int vcnt = 0;

    const int tid = threadIdx.x;
    const long total4 = 2L * (long)n_pix;   // float4 count per array

    for (long g = (long)blockIdx.x * 256 + tid; 2 * g < (long)n_pix;
         g += (long)gridDim.x * 256) {
        const long b4 = 4 * g;
        const bool in1 = (2 * g + 1) < (long)n_pix;
        const long i1 = (b4 + 1 < total4) ? b4 + 1 : total4 - 1;
        const long i2 = (b4 + 2 < total4) ? b4 + 2 : total4 - 1;
        const long i3 = (b4 + 3 < total4) ? b4 + 3 : total4 - 1;

        vf4 pA = __builtin_nontemporal_load(&preds[b4]);
        vf4 pB = __builtin_nontemporal_load(&preds[i1]);
        vf4 pC = __builtin_nontemporal_load(&preds[i2]);
        vf4 pD = __builtin_nontemporal_load(&preds[i3]);
        vf4 tA = __builtin_nontemporal_load(&tgts[b4]);
        vf4 tB = __builtin_nontemporal_load(&tgts[i1]);
        vf4 tC = __builtin_nontemporal_load(&tgts[i2]);
        vf4 tD = __builtin_nontemporal_load(&tgts[i3]);

        bool v1 = tA.x > 0.1f;            // pixel 2g
        bool v2 = in1 && (tC.x > 0.1f);   // pixel 2g+1

        // focal, pixel 2g
        {
            float x  = pA.x;
            float xt = v1 ? x : 1.f - x;
            float at = v1 ? 0.25f : 0.75f;
            float om = 1.f - xt;
            facc += -at * om * om * __logf(xt + 1e-5f);
        }
        // focal, pixel 2g+1 (masked if out of bounds)
        {
            bool vv  = tC.x > 0.1f;
            float x  = pC.x;
            float xt = vv ? x : 1.f - x;
            float at = vv ? 0.25f : 0.75f;
            float om = 1.f - xt;
            float f  = -at * om * om * __logf(xt + 1e-5f);
            facc += in1 ? f : 0.f;
        }
        vcnt += (unsigned)__builtin_popcountll(__ballot(v1));
        vcnt += (unsigned)__builtin_popcountll(__ballot(v2));

        float pd[14] = {pA.y,pA.z,pA.w, pB.x,pB.y,pB.z,pB.w,
                        pC.y,pC.z,pC.w, pD.x,pD.y,pD.z,pD.w};
        float td[14] = {tA.y,tA.z,tA.w, tB.x,tB.y,tB.z,tB.w,
                        tC.y,tC.z,tC.w, tD.x,tD.y,tD.z,tD.w};
#pragma unroll
        for (int e = 0; e < 14; ++e) {
            bool m   = (e < 7) ? v1 : v2;
            float d  = pd[e] - td[e];
            float d2 = d * d;
            float s  = __builtin_amdgcn_sqrtf(__builtin_fmaf(d, d, MU2));
            float loss = s - 0.02f;
            // bin 0: predicate is exactly m — no compare/ballot needed
            lac[0] += m ? loss : 0.f;
            float d2m = m ? d2 : -1.f;
#pragma unroll
            for (int b = 1; b < 10; ++b) {
                bool pb = d2m >= C[b];
                lac[b] += pb ? loss : 0.f;
                cnt[b] += (unsigned)__builtin_popcountll(__ballot(pb));
            }
        }
    }

    float vq[11] = { lac[0], lac[1], lac[2], lac[3], lac[4],
                     lac[5], lac[6], lac[7], lac[8], lac[9], facc };
#pragma unroll
    for (int q = 0; q < 11; ++q) vq[q] = wave_sum(vq[q]);

    __shared__ float sm[4][NQ];
    const int wave = tid >> 6, lane = tid & 63;
    if (lane == 0) {
#pragma unroll
        for (int q = 0; q < 11; ++q) sm[wave][q] = vq[q];
        sm[wave][11] = (float)vcnt;
        sm[wave][12] = 0.f;
#pragma unroll
        for (int b = 1; b < 10; ++b) sm[wave][12 + b] = (float)cnt[b];
    }
    __syncthreads();
    if (tid < NQ) {
        float v = sm[0][tid] + sm[1][tid] + sm[2][tid] + sm[3][tid];
        part[(size_t)tid * nb + blockIdx.x] = v;
    }
}

// 22 parallel blocks: block q reduces part[q][0..nb) -> red[q]
__global__ __launch_bounds__(256)
void ghm_pass2(const float* __restrict__ part, int nb, float* __restrict__ red) {
    const int q = blockIdx.x;
    const int tid = threadIdx.x;
    float v = 0.f;
    for (int i = tid; i < nb; i += 256) v += part[(size_t)q * nb + i];
    v = wave_sum(v);
    __shared__ float wv[4];
    if ((tid & 63) == 0) wv[tid >> 6] = v;
    __syncthreads();
    if (tid == 0) red[q] = wv[0] + wv[1] + wv[2] + wv[3];
}

__global__ __launch_bounds__(64)
void ghm_pass3(const float* __restrict__ red, float* __restrict__ out,
               float inv_npix) {
    if (threadIdx.x == 0) {
        float tot = fmaxf(red[11], 1.f);
        float c0  = 7.f * red[11];           // bin-0 cumulative count
        float n = 0.f, sum = 0.f;
#pragma unroll
        for (int b = 0; b < 10; ++b) {
            float ccb = (b == 0) ? c0 : red[12 + b];
            float cb  = ccb        - (b < 9 ? red[12 + b + 1] : 0.f);
            float lb  = red[b]     - (b < 9 ? red[b + 1]      : 0.f);
            if (cb > 0.f) {
                n += 1.f;
                sum += tot / fmaxf(0.3f * cb, 1e-30f) * lb;
            }
        }
        float reg = sum / fmaxf(n, 1.f) / tot;
        float cls = red[10] * inv_npix;
        out[0] = cls + reg;
        out[1] = reg;
        out[2] = cls;
    }
}

extern "C" void kernel_launch(void* const* d_in, const int* in_sizes, int n_in,
                              void* d_out, int out_size, void* d_ws, size_t ws_size,
                              hipStream_t stream) {
    const float* preds = (const float*)d_in[0];
    const float* tgts  = (const float*)d_in[1];
    const int n_pix = in_sizes[0] / 8;

    long want_nb = ((long)n_pix + 511) / 512;          // one-shot: 2 px/thread
    long cap = ((long)(ws_size / sizeof(float)) - NQ) / NQ;
    long nb_l = want_nb < cap ? want_nb : cap;
    if (nb_l < 1) nb_l = 1;
    int nb = (int)nb_l;

    float* part = (float*)d_ws;
    float* red  = part + (size_t)NQ * nb;
    ghm_pass1<<<nb, 256, 0, stream>>>((const vf4*)preds, (const vf4*)tgts,
                                      n_pix, part, nb);
    ghm_pass2<<<NQ, 256, 0, stream>>>(part, nb, red);
    ghm_pass3<<<1, 64, 0, stream>>>(red, (float*)d_out, 1.f / (float)n_pix);
}

// Round 8
// 87.861 us; speedup vs baseline: 3.6709x; 1.2169x over previous
//
#include <hip/hip_runtime.h>

// GHM loss: focal (ch 0) + GHMR (ch 1..7), 3 scalar outputs.
//
// Pass 1: ONE-SHOT grid (no grid-stride convoy; round-4: 112->70us):
//   thread g handles pixels 2g, 2g+1 via 8 independent dwordx4 loads.
//   CACHE PARTITIONING (round-7 lesson): blanket nt loads killed L3
//   residency (FETCH 143->267 MB, 70.7->107us). Instead: nt ONLY on
//   preds (streams from HBM, no L3 allocation), normal loads on tgts
//   (144 MB < 256 MB Infinity Cache -> ~full residency across replays).
//   Bin test algebraic: g*10 >= b  <=>  d^2 >= C_b = b^2*mu^2/(100-b^2).
//   Bin 0's predicate is exactly `valid` -> no compare/ballot; its count
//   c_0 = 7 * (valid pixel count), derived in the finalizer.
//   Counts b=1..9: ballot -> popcll (wave-uniform, scalar pipe).
// Pass 2: 22 blocks IN PARALLEL, block q reduces part[q][*] -> red[q].
//   (Round-6 lesson: single-block fusion = one CU reading 774 KB
//    latency-bound = 232 us. Keep the parallel stage.)
// Pass 3: 1 tiny block computes the 3 outputs from red[22].
//
// Partials layout [quantity][block], NQ = 22:
//   q 0..9  : cumulative loss sums  l_b  (loss where g*10 >= b, valid)
//   q 10    : focal sum
//   q 11    : valid pixel count
//   q 12    : unused (written 0; c_0 derived as 7*q11)
//   q 13..21: cumulative counts     c_b, b=1..9

#define NQ 22

// native vector type: __builtin_nontemporal_load rejects HIP_vector_type
typedef float vf4 __attribute__((ext_vector_type(4)));

__device__ __forceinline__ float wave_sum(float v) {
    v += __shfl_down(v, 32);
    v += __shfl_down(v, 16);
    v += __shfl_down(v, 8);
    v += __shfl_down(v, 4);
    v += __shfl_down(v, 2);
    v += __shfl_down(v, 1);
    return v;
}

__global__ __launch_bounds__(256)
void ghm_pass1(const vf4* __restrict__ preds, const vf4* __restrict__ tgts,
               int n_pix, float* __restrict__ part, int nb) {
    constexpr float MU2 = 4.0e-4f;
    const float C[10] = { -0.5f,
                          4.0404041e-6f, 1.6666667e-5f, 3.9560441e-5f,
                          7.6190476e-5f, 1.3333333e-4f, 2.2500000e-4f,
                          3.8431373e-4f, 7.1111111e-4f, 1.7052632e-3f };

    float lac[10];
#pragma unroll
    for (int b = 0; b < 10; ++b) lac[b] = 0.f;
    float facc = 0.f;
    unsigned int cnt[10] = {0,0,0,0,0,0,0,0,0,0};
    unsigned int vcnt = 0;

    const int tid = threadIdx.x;
    const long total4 = 2L * (long)n_pix;   // float4 count per array

    for (long g = (long)blockIdx.x * 256 + tid; 2 * g < (long)n_pix;
         g += (long)gridDim.x * 256) {
        const long b4 = 4 * g;
        const bool in1 = (2 * g + 1) < (long)n_pix;
        const long i1 = (b4 + 1 < total4) ? b4 + 1 : total4 - 1;
        const long i2 = (b4 + 2 < total4) ? b4 + 2 : total4 - 1;
        const long i3 = (b4 + 3 < total4) ? b4 + 3 : total4 - 1;

        // preds: nontemporal (HBM stream, keep out of L3)
        vf4 pA = __builtin_nontemporal_load(&preds[b4]);
        vf4 pB = __builtin_nontemporal_load(&preds[i1]);
        vf4 pC = __builtin_nontemporal_load(&preds[i2]);
        vf4 pD = __builtin_nontemporal_load(&preds[i3]);
        // tgts: normal loads (144 MB -> L3-resident across replays)
        vf4 tA = tgts[b4];
        vf4 tB = tgts[i1];
        vf4 tC = tgts[i2];
        vf4 tD = tgts[i3];

        bool v1 = tA.x > 0.1f;            // pixel 2g
        bool v2 = in1 && (tC.x > 0.1f);   // pixel 2g+1

        // focal, pixel 2g
        {
            float x  = pA.x;
            float xt = v1 ? x : 1.f - x;
            float at = v1 ? 0.25f : 0.75f;
            float om = 1.f - xt;
            facc += -at * om * om * __logf(xt + 1e-5f);
        }
        // focal, pixel 2g+1 (masked if out of bounds)
        {
            bool vv  = tC.x > 0.1f;
            float x  = pC.x;
            float xt = vv ? x : 1.f - x;
            float at = vv ? 0.25f : 0.75f;
            float om = 1.f - xt;
            float f  = -at * om * om * __logf(xt + 1e-5f);
            facc += in1 ? f : 0.f;
        }
        vcnt += (unsigned)__builtin_popcountll(__ballot(v1));
        vcnt += (unsigned)__builtin_popcountll(__ballot(v2));

        float pd[14] = {pA.y,pA.z,pA.w, pB.x,pB.y,pB.z,pB.w,
                        pC.y,pC.z,pC.w, pD.x,pD.y,pD.z,pD.w};
        float td[14] = {tA.y,tA.z,tA.w, tB.x,tB.y,tB.z,tB.w,
                        tC.y,tC.z,tC.w, tD.x,tD.y,tD.z,tD.w};
#pragma unroll
        for (int e = 0; e < 14; ++e) {
            bool m   = (e < 7) ? v1 : v2;
            float d  = pd[e] - td[e];
            float d2 = d * d;
            float s  = __builtin_amdgcn_sqrtf(__builtin_fmaf(d, d, MU2));
            float loss = s - 0.02f;
            // bin 0: predicate is exactly m — no compare/ballot needed
            lac[0] += m ? loss : 0.f;
            float d2m = m ? d2 : -1.f;
#pragma unroll
            for (int b = 1; b < 10; ++b) {
                bool pb = d2m >= C[b];
                lac[b] += pb ? loss : 0.f;
                cnt[b] += (unsigned)__builtin_popcountll(__ballot(pb));
            }
        }
    }

    float vq[11] = { lac[0], lac[1], lac[2], lac[3], lac[4],
                     lac[5], lac[6], lac[7], lac[8], lac[9], facc };
#pragma unroll
    for (int q = 0; q < 11; ++q) vq[q] = wave_sum(vq[q]);

    __shared__ float sm[4][NQ];
    const int wave = tid >> 6, lane = tid & 63;
    if (lane == 0) {
#pragma unroll
        for (int q = 0; q < 11; ++q) sm[wave][q] = vq[q];
        sm[wave][11] = (float)vcnt;
        sm[wave][12] = 0.f;
#pragma unroll
        for (int b = 1; b < 10; ++b) sm[wave][12 + b] = (float)cnt[b];
    }
    __syncthreads();
    if (tid < NQ) {
        float v = sm[0][tid] + sm[1][tid] + sm[2][tid] + sm[3][tid];
        part[(size_t)tid * nb + blockIdx.x] = v;
    }
}

// 22 parallel blocks: block q reduces part[q][0..nb) -> red[q]
__global__ __launch_bounds__(256)
void ghm_pass2(const float* __restrict__ part, int nb, float* __restrict__ red) {
    const int q = blockIdx.x;
    const int tid = threadIdx.x;
    float v = 0.f;
    for (int i = tid; i < nb; i += 256) v += part[(size_t)q * nb + i];
    v = wave_sum(v);
    __shared__ float wv[4];
    if ((tid & 63) == 0) wv[tid >> 6] = v;
    __syncthreads();
    if (tid == 0) red[q] = wv[0] + wv[1] + wv[2] + wv[3];
}

__global__ __launch_bounds__(64)
void ghm_pass3(const float* __restrict__ red, float* __restrict__ out,
               float inv_npix) {
    if (threadIdx.x == 0) {
        float tot = fmaxf(red[11], 1.f);
        float c0  = 7.f * red[11];           // bin-0 cumulative count
        float n = 0.f, sum = 0.f;
#pragma unroll
        for (int b = 0; b < 10; ++b) {
            float ccb = (b == 0) ? c0 : red[12 + b];
            float cb  = ccb        - (b < 9 ? red[12 + b + 1] : 0.f);
            float lb  = red[b]     - (b < 9 ? red[b + 1]      : 0.f);
            if (cb > 0.f) {
                n += 1.f;
                sum += tot / fmaxf(0.3f * cb, 1e-30f) * lb;
            }
        }
        float reg = sum / fmaxf(n, 1.f) / tot;
        float cls = red[10] * inv_npix;
        out[0] = cls + reg;
        out[1] = reg;
        out[2] = cls;
    }
}

extern "C" void kernel_launch(void* const* d_in, const int* in_sizes, int n_in,
                              void* d_out, int out_size, void* d_ws, size_t ws_size,
                              hipStream_t stream) {
    const float* preds = (const float*)d_in[0];
    const float* tgts  = (const float*)d_in[1];
    const int n_pix = in_sizes[0] / 8;

    long want_nb = ((long)n_pix + 511) / 512;          // one-shot: 2 px/thread
    long cap = ((long)(ws_size / sizeof(float)) - NQ) / NQ;
    long nb_l = want_nb < cap ? want_nb : cap;
    if (nb_l < 1) nb_l = 1;
    int nb = (int)nb_l;

    float* part = (float*)d_ws;
    float* red  = part + (size_t)NQ * nb;
    ghm_pass1<<<nb, 256, 0, stream>>>((const vf4*)preds, (const vf4*)tgts,
                                      n_pix, part, nb);
    ghm_pass2<<<NQ, 256, 0, stream>>>(part, nb, red);
    ghm_pass3<<<1, 64, 0, stream>>>(red, (float*)d_out, 1.f / (float)n_pix);
}

// Round 9
// 63.537 us; speedup vs baseline: 5.0762x; 1.3828x over previous
//
#include <hip/hip_runtime.h>

// GHM loss: focal (ch 0) + GHMR (ch 1..7), 3 scalar outputs.
//
// Empirical model from rounds 4/7/8:  dur ~= 29us + FETCH * 0.29us/MB.
//   - nt loads in ANY placement only increase FETCH (L3 default retention
//     ~50% of the 288MB stream is the best achievable) -> plain loads.
//   - Attack the intercept + marginal rate: 4 px/thread = 16 independent
//     dwordx4 loads in flight per lane, half the waves, and (n_pix %
//     1024 == 0) a clean path with NO bounds clamps.
// Pass 1 (clean): thread g handles pixels 4g..4g+3.
//   Bin test algebraic: g*10 >= b  <=>  d^2 >= C_b = b^2*mu^2/(100-b^2).
//   Bin 0 predicate == valid -> no compare/ballot; c_0 = 7*q11 in pass3.
//   Counts b=1..9: ballot -> popcll (scalar pipe).
// Pass 2: 22 blocks in parallel (round-6 lesson: never single-block this).
// Pass 3: tiny finalize.
//
// Partials layout [quantity][block], NQ = 22:
//   q 0..9 : cumulative loss sums; q 10: focal; q 11: valid count;
//   q 12: zero (c_0 derived); q 13..21: cumulative counts b=1..9.

#define NQ 22

typedef float vf4 __attribute__((ext_vector_type(4)));

__device__ __forceinline__ float wave_sum(float v) {
    v += __shfl_down(v, 32);
    v += __shfl_down(v, 16);
    v += __shfl_down(v, 8);
    v += __shfl_down(v, 4);
    v += __shfl_down(v, 2);
    v += __shfl_down(v, 1);
    return v;
}

__device__ __forceinline__ void ghm_epilogue(float lac[10], float facc,
                                             unsigned vcnt, const unsigned cnt[10],
                                             float* __restrict__ part, int nb) {
    const int tid = threadIdx.x;
    float vq[11] = { lac[0], lac[1], lac[2], lac[3], lac[4],
                     lac[5], lac[6], lac[7], lac[8], lac[9], facc };
#pragma unroll
    for (int q = 0; q < 11; ++q) vq[q] = wave_sum(vq[q]);

    __shared__ float sm[4][NQ];
    const int wave = tid >> 6, lane = tid & 63;
    if (lane == 0) {
#pragma unroll
        for (int q = 0; q < 11; ++q) sm[wave][q] = vq[q];
        sm[wave][11] = (float)vcnt;
        sm[wave][12] = 0.f;
#pragma unroll
        for (int b = 1; b < 10; ++b) sm[wave][12 + b] = (float)cnt[b];
    }
    __syncthreads();
    if (tid < NQ) {
        float v = sm[0][tid] + sm[1][tid] + sm[2][tid] + sm[3][tid];
        part[(size_t)tid * nb + blockIdx.x] = v;
    }
}

// ---------------- clean path: n_pix % 1024 == 0, 4 px/thread ----------------
__global__ __launch_bounds__(256)
void ghm_pass1_c4(const vf4* __restrict__ preds, const vf4* __restrict__ tgts,
                  int n_pix, float* __restrict__ part, int nb) {
    constexpr float MU2 = 4.0e-4f;
    const float C[10] = { -0.5f,
                          4.0404041e-6f, 1.6666667e-5f, 3.9560441e-5f,
                          7.6190476e-5f, 1.3333333e-4f, 2.2500000e-4f,
                          3.8431373e-4f, 7.1111111e-4f, 1.7052632e-3f };

    float lac[10];
#pragma unroll
    for (int b = 0; b < 10; ++b) lac[b] = 0.f;
    float facc = 0.f;
    unsigned int cnt[10] = {0,0,0,0,0,0,0,0,0,0};
    unsigned int vcnt = 0;

    const int tid = threadIdx.x;

    for (long g = (long)blockIdx.x * 256 + tid; 4 * g < (long)n_pix;
         g += (long)gridDim.x * 256) {
        const long b4 = 8 * g;       // 4 pixels = 8 float4 per array
        vf4 p[8], t[8];
#pragma unroll
        for (int j = 0; j < 8; ++j) p[j] = preds[b4 + j];
#pragma unroll
        for (int j = 0; j < 8; ++j) t[j] = tgts[b4 + j];

        bool vld[4];
#pragma unroll
        for (int i = 0; i < 4; ++i) {
            vld[i] = t[2 * i].x > 0.1f;
            float x  = p[2 * i].x;
            float xt = vld[i] ? x : 1.f - x;
            float at = vld[i] ? 0.25f : 0.75f;
            float om = 1.f - xt;
            facc += -at * om * om * __logf(xt + 1e-5f);
            vcnt += (unsigned)__builtin_popcountll(__ballot(vld[i]));
        }

#pragma unroll
        for (int i = 0; i < 4; ++i) {
            float pd[7] = { p[2*i].y, p[2*i].z, p[2*i].w,
                            p[2*i+1].x, p[2*i+1].y, p[2*i+1].z, p[2*i+1].w };
            float td[7] = { t[2*i].y, t[2*i].z, t[2*i].w,
                            t[2*i+1].x, t[2*i+1].y, t[2*i+1].z, t[2*i+1].w };
            const bool m = vld[i];
#pragma unroll
            for (int e = 0; e < 7; ++e) {
                float d  = pd[e] - td[e];
                float d2 = d * d;
                float s  = __builtin_amdgcn_sqrtf(__builtin_fmaf(d, d, MU2));
                float loss = s - 0.02f;
                lac[0] += m ? loss : 0.f;        // bin 0 == valid
                float d2m = m ? d2 : -1.f;
#pragma unroll
                for (int b = 1; b < 10; ++b) {
                    bool pb = d2m >= C[b];
                    lac[b] += pb ? loss : 0.f;
                    cnt[b] += (unsigned)__builtin_popcountll(__ballot(pb));
                }
            }
        }
    }
    ghm_epilogue(lac, facc, vcnt, cnt, part, nb);
}

// ---------------- generic path: 2 px/thread with clamps ----------------
__global__ __launch_bounds__(256)
void ghm_pass1_g2(const vf4* __restrict__ preds, const vf4* __restrict__ tgts,
                  int n_pix, float* __restrict__ part, int nb) {
    constexpr float MU2 = 4.0e-4f;
    const float C[10] = { -0.5f,
                          4.0404041e-6f, 1.6666667e-5f, 3.9560441e-5f,
                          7.6190476e-5f, 1.3333333e-4f, 2.2500000e-4f,
                          3.8431373e-4f, 7.1111111e-4f, 1.7052632e-3f };

    float lac[10];
#pragma unroll
    for (int b = 0; b < 10; ++b) lac[b] = 0.f;
    float facc = 0.f;
    unsigned int cnt[10] = {0,0,0,0,0,0,0,0,0,0};
    unsigned int vcnt = 0;

    const int tid = threadIdx.x;
    const long total4 = 2L * (long)n_pix;

    for (long g = (long)blockIdx.x * 256 + tid; 2 * g < (long)n_pix;
         g += (long)gridDim.x * 256) {
        const long b4 = 4 * g;
        const bool in1 = (2 * g + 1) < (long)n_pix;
        const long i1 = (b4 + 1 < total4) ? b4 + 1 : total4 - 1;
        const long i2 = (b4 + 2 < total4) ? b4 + 2 : total4 - 1;
        const long i3 = (b4 + 3 < total4) ? b4 + 3 : total4 - 1;

        vf4 pA = preds[b4], pB = preds[i1], pC = preds[i2], pD = preds[i3];
        vf4 tA = tgts[b4],  tB = tgts[i1],  tC = tgts[i2],  tD = tgts[i3];

        bool v1 = tA.x > 0.1f;
        bool v2 = in1 && (tC.x > 0.1f);
        {
            float x = pA.x;
            float xt = v1 ? x : 1.f - x;
            float at = v1 ? 0.25f : 0.75f;
            float om = 1.f - xt;
            facc += -at * om * om * __logf(xt + 1e-5f);
        }
        {
            bool vv = tC.x > 0.1f;
            float x = pC.x;
            float xt = vv ? x : 1.f - x;
            float at = vv ? 0.25f : 0.75f;
            float om = 1.f - xt;
            float f = -at * om * om * __logf(xt + 1e-5f);
            facc += in1 ? f : 0.f;
        }
        vcnt += (unsigned)__builtin_popcountll(__ballot(v1));
        vcnt += (unsigned)__builtin_popcountll(__ballot(v2));

        float pd[14] = {pA.y,pA.z,pA.w, pB.x,pB.y,pB.z,pB.w,
                        pC.y,pC.z,pC.w, pD.x,pD.y,pD.z,pD.w};
        float td[14] = {tA.y,tA.z,tA.w, tB.x,tB.y,tB.z,tB.w,
                        tC.y,tC.z,tC.w, tD.x,tD.y,tD.z,tD.w};
#pragma unroll
        for (int e = 0; e < 14; ++e) {
            bool m   = (e < 7) ? v1 : v2;
            float d  = pd[e] - td[e];
            float d2 = d * d;
            float s  = __builtin_amdgcn_sqrtf(__builtin_fmaf(d, d, MU2));
            float loss = s - 0.02f;
            lac[0] += m ? loss : 0.f;
            float d2m = m ? d2 : -1.f;
#pragma unroll
            for (int b = 1; b < 10; ++b) {
                bool pb = d2m >= C[b];
                lac[b] += pb ? loss : 0.f;
                cnt[b] += (unsigned)__builtin_popcountll(__ballot(pb));
            }
        }
    }
    ghm_epilogue(lac, facc, vcnt, cnt, part, nb);
}

// 22 parallel blocks: block q reduces part[q][0..nb) -> red[q]
__global__ __launch_bounds__(256)
void ghm_pass2(const float* __restrict__ part, int nb, float* __restrict__ red) {
    const int q = blockIdx.x;
    const int tid = threadIdx.x;
    float v = 0.f;
    for (int i = tid; i < nb; i += 256) v += part[(size_t)q * nb + i];
    v = wave_sum(v);
    __shared__ float wv[4];
    if ((tid & 63) == 0) wv[tid >> 6] = v;
    __syncthreads();
    if (tid == 0) red[q] = wv[0] + wv[1] + wv[2] + wv[3];
}

__global__ __launch_bounds__(64)
void ghm_pass3(const float* __restrict__ red, float* __restrict__ out,
               float inv_npix) {
    if (threadIdx.x == 0) {
        float tot = fmaxf(red[11], 1.f);
        float c0  = 7.f * red[11];
        float n = 0.f, sum = 0.f;
#pragma unroll
        for (int b = 0; b < 10; ++b) {
            float ccb = (b == 0) ? c0 : red[12 + b];
            float cb  = ccb    - (b < 9 ? red[12 + b + 1] : 0.f);
            float lb  = red[b] - (b < 9 ? red[b + 1]      : 0.f);
            if (cb > 0.f) {
                n += 1.f;
                sum += tot / fmaxf(0.3f * cb, 1e-30f) * lb;
            }
        }
        float reg = sum / fmaxf(n, 1.f) / tot;
        float cls = red[10] * inv_npix;
        out[0] = cls + reg;
        out[1] = reg;
        out[2] = cls;
    }
}

extern "C" void kernel_launch(void* const* d_in, const int* in_sizes, int n_in,
                              void* d_out, int out_size, void* d_ws, size_t ws_size,
                              hipStream_t stream) {
    const float* preds = (const float*)d_in[0];
    const float* tgts  = (const float*)d_in[1];
    const int n_pix = in_sizes[0] / 8;

    const bool clean = (n_pix % 1024) == 0;
    long want_nb = clean ? (long)n_pix / 1024 : ((long)n_pix + 511) / 512;
    long cap = ((long)(ws_size / sizeof(float)) - NQ) / NQ;
    long nb_l = want_nb < cap ? want_nb : cap;
    if (nb_l < 1) nb_l = 1;
    int nb = (int)nb_l;

    float* part = (float*)d_ws;
    float* red  = part + (size_t)NQ * nb;
    if (clean)
        ghm_pass1_c4<<<nb, 256, 0, stream>>>((const vf4*)preds, (const vf4*)tgts,
                                             n_pix, part, nb);
    else
        ghm_pass1_g2<<<nb, 256, 0, stream>>>((const vf4*)preds, (const vf4*)tgts,
                                             n_pix, part, nb);
    ghm_pass2<<<NQ, 256, 0, stream>>>(part, nb, red);
    ghm_pass3<<<1, 64, 0, stream>>>(red, (float*)d_out, 1.f / (float)n_pix);
}